// Round 14
// baseline (549.621 us; speedup 1.0000x reference)
//
#include <hip/hip_runtime.h>
#include <stdint.h>

// ---------------------------------------------------------------------------
// RGNN layer: h_t = relu( sum_k L^{k+1} (x_t W_k + h_{t-1} H_k) ), h_{-1}=0
// B=8 T=16 N=1024 F=128 K=4.
//
//   Lcat [1024 n][4096 q],  q=(k,m):  Lcat[n][k*1024+m] = (L^{k+1})[n][m]
//   S    [8192 c=(b,m)][4096 q]     : S layout S[b][g][k][m]
//   Z[n][(b,g)] = sum_q Lcat[n][q] * S[..]; h = relu(Z); out = h (f32)
//
// Laws (r4,7,8,11,12): LDS staging mandatory; no in-kernel cross-block
// fences; split-K for L2 residency (<4MB/XCD); 16x16 frags conflict-free
// w/ XOR swizzle; GEMM time tracks LDS bytes M*N*K*2*(1/WM+1/WN) -> 64x64
// waves @ 2 blk/CU optimal; setprio neutral.
//
// Round 14: round-13 fusion with the k_setup grid bug FIXED (WH section
// needed 256 blocks for 4*128*128 = 65536 elements; had 64 -> taps 1..3
// poisoned). combine(t-1) fused into feat(t); loop = {fused, graph} x16
// + final combine. 37 dispatches total.
// ---------------------------------------------------------------------------

typedef __bf16 bf16_t;
typedef __bf16 bf16x4 __attribute__((ext_vector_type(4)));
typedef __bf16 bf16x8 __attribute__((ext_vector_type(8)));
typedef float  f32x4  __attribute__((ext_vector_type(4)));

__device__ __forceinline__ void gload_lds16(const void* g, void* l) {
    __builtin_amdgcn_global_load_lds(
        (const __attribute__((address_space(1))) void*)g,
        (__attribute__((address_space(3))) void*)l,
        16, 0, 0);
}

template<int N> __device__ __forceinline__ void wait_vmcnt() {
    if constexpr (N == 0)       asm volatile("s_waitcnt vmcnt(0)" ::: "memory");
    else if constexpr (N == 2)  asm volatile("s_waitcnt vmcnt(2)" ::: "memory");
    else if constexpr (N == 3)  asm volatile("s_waitcnt vmcnt(3)" ::: "memory");
    else if constexpr (N == 4)  asm volatile("s_waitcnt vmcnt(4)" ::: "memory");
    else if constexpr (N == 6)  asm volatile("s_waitcnt vmcnt(6)" ::: "memory");
    else if constexpr (N == 8)  asm volatile("s_waitcnt vmcnt(8)" ::: "memory");
    else                        asm volatile("s_waitcnt vmcnt(16)" ::: "memory");
}

// ---- merged setup: L->Lcat/Lt, W/H->WHT, x->bf16 ---------------------------
// grid 8448: [0,4096) L, [4096,4352) WH (256 blocks = 65536 threads),
// [4352,8448) x (4096 blocks, 4 grid-stride iterations).

__global__ void k_setup(const float* __restrict__ x, const float* __restrict__ L,
                        const float* __restrict__ W, const float* __restrict__ H,
                        bf16_t* __restrict__ xb, bf16_t* __restrict__ Lcat,
                        bf16_t* __restrict__ Lt, bf16_t* __restrict__ WHT) {
    int bid = blockIdx.x;
    if (bid < 4096) {                       // L: 1024x1024
        int idx = bid * 256 + threadIdx.x;
        int n = idx >> 10, m = idx & 1023;
        float v = L[idx];
        Lcat[n * 4096 + m] = (bf16_t)v;
        Lt[m * 1024 + n]   = (bf16_t)v;
    } else if (bid < 4352) {                // WH: 4*128*128 = 65536
        int idx = (bid - 4096) * 256 + threadIdx.x;
        int k = idx >> 14, f = (idx >> 7) & 127, g = idx & 127;
        WHT[(k * 128 + g) * 256 + f]       = (bf16_t)W[idx];
        WHT[(k * 128 + g) * 256 + 128 + f] = (bf16_t)H[idx];
    } else {                                // x: 4194304 float4, grid-stride
        int i = (bid - 4352) * 256 + threadIdx.x;
        for (; i < 4194304; i += 4096 * 256) {
            float4 v = reinterpret_cast<const float4*>(x)[i];
            bf16x4 o = { (bf16_t)v.x, (bf16_t)v.y, (bf16_t)v.z, (bf16_t)v.w };
            reinterpret_cast<bf16x4*>(xb)[i] = o;
        }
    }
}

// ---- combine (final step + fallback): relu(sum Zp) -> h, out ---------------

__global__ __launch_bounds__(256)
void k_combine8(const bf16_t* __restrict__ Zp,  // [8][1024][1024] (n, c=(b,g))
                bf16_t* __restrict__ h, float* __restrict__ out, int t) {
    int i = blockIdx.x * 256 + threadIdx.x;
    int n  = i >> 7;
    int c8 = (i & 127) * 8;
    size_t o = (size_t)n * 1024 + c8;
    float s[8] = {};
    #pragma unroll
    for (int z = 0; z < 8; ++z) {
        bf16x8 v = *reinterpret_cast<const bf16x8*>(Zp + (size_t)z * 1048576 + o);
        #pragma unroll
        for (int j = 0; j < 8; ++j) s[j] += (float)v[j];
    }
    bf16x8 hb;
    float4 o0, o1;
    #pragma unroll
    for (int j = 0; j < 8; ++j) { s[j] = fmaxf(s[j], 0.f); hb[j] = (bf16_t)s[j]; }
    o0.x = s[0]; o0.y = s[1]; o0.z = s[2]; o0.w = s[3];
    o1.x = s[4]; o1.y = s[5]; o1.z = s[6]; o1.w = s[7];
    int b = c8 >> 7, g = c8 & 127;
    *reinterpret_cast<bf16x8*>(h + (size_t)b * 131072 + (size_t)n * 128 + g) = hb;
    float* op = out + (size_t)b * 2097152 + (size_t)t * 131072
                    + (size_t)n * 128 + g;
    *reinterpret_cast<float4*>(op)     = o0;
    *reinterpret_cast<float4*>(op + 4) = o1;
}

// ---- fused combine(t-1) + feature GEMM(t) ----------------------------------
// grid 256 (1D, XCD-swizzled). Block = 32 c-cols x all 128 g x all 4 taps.
// Phase 1: h rows for this block's 32 (b,m) from Zp (8 slices, fixed order,
// f32 sum, relu) -> swizzled LDS B-subtiles ks=2,3; out(t-1) written.
// Phase 2: S_k[g][c] = WHT_k @ [x|h]^T, 16 (tap,kstep) iterations, 3-buf A.
template<bool FIRST>
__global__ __launch_bounds__(256)
void k_fused(const bf16_t* __restrict__ WHT, const bf16_t* __restrict__ xb,
             const bf16_t* __restrict__ Zp, bf16_t* __restrict__ Sbuf,
             float* __restrict__ out, int t)
{
    __shared__ __align__(16) bf16_t BsF[4 * 32 * 64];   // [ks][32 c][64 k]
    __shared__ __align__(16) bf16_t AsF[3 * 128 * 64];  // [buf][128 g][64 k]

    const int tid  = threadIdx.x;
    const int lane = tid & 63;
    const int wave = tid >> 6;
    const int wm = wave >> 1, wn = wave & 1;   // WM=64 g, WN=16 c

    const int id = blockIdx.x;
    const int bx = (id & 7) * 32 + (id >> 3);  // bijective XCD swizzle, 256
    const int c0 = bx * 32;
    const int b  = c0 >> 10;                   // uniform per block
    const int mb = c0 & 1023;

    // ---- issue x-half B + first two A tiles (DMA overlaps phase 1) ----
    #pragma unroll
    for (int ks = 0; ks < 2; ++ks) {
        int off = tid * 16;                    // byte within subtile
        int row = off >> 7;
        int kel = ((off ^ ((row & 7) << 4)) & 127) >> 1;
        const bf16_t* src = xb + (size_t)b * 2097152 + (size_t)t * 131072
                          + (size_t)(mb + row) * 128 + ks * 64 + kel;
        gload_lds16(src, (char*)BsF + ks * 4096 + off);
    }
    auto stageA = [&](int bufi, int s) {       // s = tap*4 + kstep
        const int k = s >> 2, st = s & 3;
        #pragma unroll
        for (int i = 0; i < 4; ++i) {
            int chunk = i * 256 + tid;
            int off = chunk * 16;
            int row = off >> 7;
            int kel = ((off ^ ((row & 7) << 4)) & 127) >> 1;
            const bf16_t* src = WHT + (size_t)(k * 128 + row) * 256
                              + st * 64 + kel;
            gload_lds16(src, (char*)AsF + bufi * 16384 + off);
        }
    };
    stageA(0, 0);
    stageA(1, 1);

    // ---- phase 1: combine(t-1) for this block's 32 rows ----
    {
        const int r  = tid >> 3;               // c-row 0..31
        const int g0 = (tid & 7) * 16;         // g base
        float s[16];
        #pragma unroll
        for (int j = 0; j < 16; ++j) s[j] = 0.f;
        if (!FIRST) {
            size_t o = (size_t)(mb + r) * 1024 + b * 128 + g0;
            #pragma unroll
            for (int z = 0; z < 8; ++z) {
                bf16x8 v0 = *reinterpret_cast<const bf16x8*>(
                    Zp + (size_t)z * 1048576 + o);
                bf16x8 v1 = *reinterpret_cast<const bf16x8*>(
                    Zp + (size_t)z * 1048576 + o + 8);
                #pragma unroll
                for (int j = 0; j < 8; ++j) {
                    s[j]     += (float)v0[j];
                    s[8 + j] += (float)v1[j];
                }
            }
        }
        bf16x8 hv[2];
        #pragma unroll
        for (int j = 0; j < 16; ++j) {
            s[j] = fmaxf(s[j], 0.f);
            hv[j >> 3][j & 7] = (bf16_t)s[j];
        }
        const int ks  = 2 + (g0 >> 6);         // h subtile
        const int kkb = g0 & 63;
        #pragma unroll
        for (int j = 0; j < 2; ++j) {
            int kk = kkb + j * 8;
            int byte = ks * 4096 + ((r * 128 + kk * 2) ^ ((r & 7) << 4));
            *reinterpret_cast<bf16x8*>((char*)BsF + byte) = hv[j];
        }
        if (!FIRST) {
            float* op = out + (size_t)b * 2097152 + (size_t)(t - 1) * 131072
                      + (size_t)(mb + r) * 128 + g0;
            float4 o0, o1, o2, o3;
            o0.x=s[0];  o0.y=s[1];  o0.z=s[2];  o0.w=s[3];
            o1.x=s[4];  o1.y=s[5];  o1.z=s[6];  o1.w=s[7];
            o2.x=s[8];  o2.y=s[9];  o2.z=s[10]; o2.w=s[11];
            o3.x=s[12]; o3.y=s[13]; o3.z=s[14]; o3.w=s[15];
            *reinterpret_cast<float4*>(op)      = o0;
            *reinterpret_cast<float4*>(op + 4)  = o1;
            *reinterpret_cast<float4*>(op + 8)  = o2;
            *reinterpret_cast<float4*>(op + 12) = o3;
        }
    }
    __syncthreads();   // h in LDS visible; prologue DMA drained here too

    // ---- phase 2: 16 (tap,kstep) iterations, 3-buf counted A pipeline ----
    f32x4 acc[4] = {};
    bf16x4 outv[4][4];
    #pragma unroll
    for (int s = 0; s < 16; ++s) {
        if (s < 15) wait_vmcnt<4>(); else wait_vmcnt<0>();
        __builtin_amdgcn_s_barrier();
        __builtin_amdgcn_sched_barrier(0);
        if (s + 2 < 16) stageA((s + 2) % 3, s + 2);

        const int abase = (s % 3) * 16384;
        const int bbase = (s & 3) * 4096;
        #pragma unroll
        for (int kk = 0; kk < 2; ++kk) {
            bf16x8 af[4], bfr;
            const int klane = (kk * 32 + (lane >> 4) * 8) * 2;
            #pragma unroll
            for (int mf = 0; mf < 4; ++mf) {
                int row = wm * 64 + mf * 16 + (lane & 15);
                int bo = (row * 128 + klane) ^ ((row & 7) << 4);
                af[mf] = *reinterpret_cast<const bf16x8*>(
                             (char*)AsF + abase + bo);
            }
            {
                int row = wn * 16 + (lane & 15);
                int bo = (row * 128 + klane) ^ ((row & 7) << 4);
                bfr = *reinterpret_cast<const bf16x8*>(
                          (char*)BsF + bbase + bo);
            }
            #pragma unroll
            for (int mf = 0; mf < 4; ++mf)
                acc[mf] = __builtin_amdgcn_mfma_f32_16x16x32_bf16(
                    af[mf], bfr, acc[mf], 0, 0, 0);
        }
        __builtin_amdgcn_sched_barrier(0);
        if ((s & 3) == 3) {                    // tap finished -> park in regs
            const int k = s >> 2;
            #pragma unroll
            for (int mf = 0; mf < 4; ++mf) {
                #pragma unroll
                for (int r2 = 0; r2 < 4; ++r2)
                    outv[k][mf][r2] = (bf16_t)acc[mf][r2];
                acc[mf] = (f32x4){0.f, 0.f, 0.f, 0.f};
            }
        }
    }

    // ---- write S: col=(b,m), row=g; S[b][g][k][m] ----
    const int col = c0 + wn * 16 + (lane & 15);
    #pragma unroll
    for (int k = 0; k < 4; ++k) {
        #pragma unroll
        for (int mf = 0; mf < 4; ++mf) {
            int gb = wm * 64 + mf * 16 + ((lane >> 4) * 4);
            #pragma unroll
            for (int r2 = 0; r2 < 4; ++r2) {
                Sbuf[(size_t)(col >> 10) * 524288 + (size_t)(gb + r2) * 4096
                     + (size_t)k * 1024 + (col & 1023)] = outv[k][mf][r2];
            }
        }
    }
}

// ---- GEMM body (16x16x32 MFMA, counted-vmcnt pipeline, NBUF=2 or 3) --------
template<int BM, int BN, int GX, int GY, int GZ, int KTOT,
         int EPI, int BADDR, int ZK, int DEC, int NBUF>
__device__ __forceinline__
void gemm_body(const bf16_t* __restrict__ A, int lda,
               const bf16_t* __restrict__ BT, int ldbt,
               const bf16_t* __restrict__ B2,
               bf16_t* __restrict__ Cb, float* __restrict__ Cf,
               int ldc, int t)
{
    constexpr int BK = 64;
    constexpr int WM = BM / 2, WN = BN / 2;
    constexpr int MF = WM / 16, NF = WN / 16;
    constexpr int NT = KTOT / BK;
    constexpr int NWG = GX * GY * GZ;
    constexpr int ACH = BM * 8;
    constexpr int BCH = BN * 8;
    constexpr int LPT = (ACH + BCH) / 256;

    __shared__ __align__(16) bf16_t As[NBUF][BM * BK];
    __shared__ __align__(16) bf16_t Bs[NBUF][BN * BK];

    const int tid  = threadIdx.x;
    const int lane = tid & 63;
    const int wave = tid >> 6;
    const int wm = wave >> 1, wn = wave & 1;

    const int id  = blockIdx.x;
    const int swz = (id & 7) * (NWG / 8) + (id >> 3);
    int bx, by, bz;
    if (DEC == 0) {
        bx = swz % GX; by = (swz / GX) % GY; bz = swz / (GX * GY);
    } else {
        by = swz % GY; bz = (swz / GY) % GZ; bx = swz / (GY * GZ);
    }

    const int m0 = by * BM;
    const int c0 = bx * BN;
    const int kb_ = bz;

    const bf16_t* Ap = (EPI == 1) ? (A + kb_ * 128 * 256) : A;

    f32x4 acc[MF][NF] = {};

    auto stage = [&](int bufi, int kt) {
        const int q0 = kt * BK + (ZK > 0 ? kb_ * ZK : 0);
        #pragma unroll
        for (int i = 0; i < ACH / 256; ++i) {
            int chunk = i * 256 + tid;
            int off = chunk * 16;
            int row = off >> 7;
            int kel = ((off ^ ((row & 7) << 4)) & 127) >> 1;
            const bf16_t* src = Ap + (size_t)(m0 + row) * lda + (q0 + kel);
            gload_lds16(src, (char*)(&As[bufi][0]) + off);
        }
        #pragma unroll
        for (int i = 0; i < BCH / 256; ++i) {
            int chunk = i * 256 + tid;
            int off = chunk * 16;
            int row = off >> 7;
            int kel = ((off ^ ((row & 7) << 4)) & 127) >> 1;
            int c = c0 + row;
            const bf16_t* src;
            if (BADDR == 0) {
                src = BT + (size_t)c * ldbt + (q0 + kel);
            } else {
                int f = q0 + kel;
                if (q0 < 128) {
                    src = BT + (size_t)(c >> 10) * 2097152
                             + (size_t)t * 131072
                             + (size_t)(c & 1023) * 128 + f;
                } else {
                    src = B2 + (size_t)c * 128 + (f - 128);
                }
            }
            gload_lds16(src, (char*)(&Bs[bufi][0]) + off);
        }
    };

    auto compute = [&](int cur) {
        #pragma unroll
        for (int kk = 0; kk < 2; ++kk) {
            bf16x8 af[MF], bfr[NF];
            const int klane = (kk * 32 + (lane >> 4) * 8) * 2;
            #pragma unroll
            for (int mf = 0; mf < MF; ++mf) {
                int row = wm * WM + mf * 16 + (lane & 15);
                int bo = (row * 128 + klane) ^ ((row & 7) << 4);
                af[mf] = *reinterpret_cast<const bf16x8*>(
                             (const char*)(&As[cur][0]) + bo);
            }
            #pragma unroll
            for (int nf = 0; nf < NF; ++nf) {
                int row = wn * WN + nf * 16 + (lane & 15);
                int bo = (row * 128 + klane) ^ ((row & 7) << 4);
                bfr[nf] = *reinterpret_cast<const bf16x8*>(
                              (const char*)(&Bs[cur][0]) + bo);
            }
            #pragma unroll
            for (int mf = 0; mf < MF; ++mf)
                #pragma unroll
                for (int nf = 0; nf < NF; ++nf)
                    acc[mf][nf] = __builtin_amdgcn_mfma_f32_16x16x32_bf16(
                        af[mf], bfr[nf], acc[mf][nf], 0, 0, 0);
        }
    };

    if constexpr (NBUF == 3) {
        stage(0, 0);
        stage(1, 1);
        for (int kt = 0; kt < NT; ++kt) {
            if (kt < NT - 1) wait_vmcnt<LPT>(); else wait_vmcnt<0>();
            __builtin_amdgcn_s_barrier();
            __builtin_amdgcn_sched_barrier(0);
            if (kt + 2 < NT) stage((kt + 2) % 3, kt + 2);
            compute(kt % 3);
            __builtin_amdgcn_sched_barrier(0);
        }
    } else {
        stage(0, 0);
        stage(1, 1);
        for (int kt = 0; kt < NT; ++kt) {
            if (kt > 0 && kt + 1 < NT) {
                __builtin_amdgcn_s_barrier();
                stage((kt + 1) & 1, kt + 1);
            }
            if (kt + 1 < NT) wait_vmcnt<LPT>();
            else             wait_vmcnt<0>();
            __builtin_amdgcn_s_barrier();
            __builtin_amdgcn_sched_barrier(0);
            compute(kt & 1);
            __builtin_amdgcn_sched_barrier(0);
        }
    }

    #pragma unroll
    for (int mf = 0; mf < MF; ++mf) {
        #pragma unroll
        for (int nf = 0; nf < NF; ++nf) {
            f32x4 v = acc[mf][nf];
            int col   = c0 + wn * WN + nf * 16 + (lane & 15);
            int rbase = m0 + wm * WM + mf * 16 + ((lane >> 4) * 4);
            #pragma unroll
            for (int r = 0; r < 4; ++r) {
                int row = rbase + r;
                float val = v[r];
                if (EPI == 0) {
                    Cb[(size_t)row * ldc + col] = (bf16_t)val;
                } else if (EPI == 1) {
                    Cb[(size_t)(col >> 10) * 524288 + (size_t)row * 4096
                       + (size_t)kb_ * 1024 + (col & 1023)] = (bf16_t)val;
                } else if (EPI == 2) {
                    val = fmaxf(val, 0.f);
                    int b = col >> 7, g = col & 127;
                    Cb[(size_t)b * 131072 + (size_t)row * 128 + g] = (bf16_t)val;
                    Cf[(size_t)b * 2097152 + (size_t)t * 131072
                       + (size_t)row * 128 + g] = val;
                } else {
                    Cb[(size_t)kb_ * 1048576 + (size_t)row * 1024 + col]
                        = (bf16_t)val;
                }
            }
        }
    }
}

// ---- flavor wrappers --------------------------------------------------------

__global__ __launch_bounds__(256)
void k_chain(const bf16_t* __restrict__ A, const bf16_t* __restrict__ BT,
             bf16_t* __restrict__ Cb) {
    gemm_body<64, 64, 16, 16, 1, 1024, 0, 0, 0, 0, 3>(
        A, 4096, BT, 1024, nullptr, Cb, nullptr, 4096, 0);
}

__global__ __launch_bounds__(256)
void k_feat(const bf16_t* __restrict__ WHT, const bf16_t* __restrict__ xb,
            const bf16_t* __restrict__ h, bf16_t* __restrict__ Sbuf, int t) {
    // fallback path only
    gemm_body<128, 64, 128, 1, 4, 256, 1, 1, 0, 1, 3>(
        WHT, 256, xb, 0, h, Sbuf, nullptr, 0, t);
}

__global__ __launch_bounds__(256)
void k_graph(const bf16_t* __restrict__ Lcat, const bf16_t* __restrict__ Sbuf,
             bf16_t* __restrict__ Zp) {
    gemm_body<128, 128, 8, 8, 8, 512, 3, 0, 512, 0, 2>(
        Lcat, 4096, Sbuf, 4096, nullptr, Zp, nullptr, 0, 0);
}

__global__ __launch_bounds__(256)
void k_graph_ns(const bf16_t* __restrict__ Lcat, const bf16_t* __restrict__ Sbuf,
                bf16_t* __restrict__ h, float* __restrict__ out, int t) {
    gemm_body<128, 128, 8, 8, 1, 4096, 2, 0, 0, 0, 3>(
        Lcat, 4096, Sbuf, 4096, nullptr, h, out, 0, t);
}

// ---- launch ---------------------------------------------------------------

extern "C" void kernel_launch(void* const* d_in, const int* in_sizes, int n_in,
                              void* d_out, int out_size, void* d_ws, size_t ws_size,
                              hipStream_t stream) {
    const float* x = (const float*)d_in[0];   // [8][16][1024][128]
    const float* L = (const float*)d_in[1];   // [1024][1024]
    const float* W = (const float*)d_in[2];   // [4][128][128]
    const float* H = (const float*)d_in[3];   // [4][128][128]
    float* out = (float*)d_out;               // [8][16][1024][128]

    char* ws = (char*)d_ws;
    bf16_t* xb   = (bf16_t*)(ws);              // 33,554,432 B
    bf16_t* Lcat = (bf16_t*)(ws + 33554432);   //  8,388,608 B [1024][4096]
    bf16_t* Lt   = (bf16_t*)(ws + 41943040);   //  2,097,152 B
    bf16_t* WHT  = (bf16_t*)(ws + 44040192);   //    262,144 B
    bf16_t* Sbuf = (bf16_t*)(ws + 44302336);   //  8,388,608 B (S layout)
    bf16_t* h    = (bf16_t*)(ws + 52690944);   //  2,097,152 B (fallback only)
    bf16_t* Zp   = (bf16_t*)(ws + 54788096);   // 16,777,216 B [8][1024][1024]
    if (ws_size < 54788096u) return;
    const bool bigws = (ws_size >= 71565312u);

    k_setup<<<8448, 256, 0, stream>>>(x, L, W, H, xb, Lcat, Lt, WHT);

    // L-power chain: block p = block(p-1) @ L (M=N=K=1024), 256 WGs
    for (int p = 1; p < 4; ++p) {
        k_chain<<<256, 256, 0, stream>>>(Lcat + (p - 1) * 1024, Lt,
                                         Lcat + p * 1024);
    }

    if (bigws) {
        for (int t = 0; t < 16; ++t) {
            // fused: combine(t-1) [h -> LDS, out(t-1)] + feat(t) -> Sbuf
            if (t == 0)
                k_fused<true><<<256, 256, 0, stream>>>(WHT, xb, Zp, Sbuf, out, t);
            else
                k_fused<false><<<256, 256, 0, stream>>>(WHT, xb, Zp, Sbuf, out, t);
            // graph: Zp[z] = Lcat[:,z*512:+512] @ S[z], split-K=8, 512 WGs
            k_graph<<<512, 256, 0, stream>>>(Lcat, Sbuf, Zp);
        }
        // final combine for t=15 (h write unused)
        k_combine8<<<512, 256, 0, stream>>>(Zp, h, out, 15);
    } else {
        hipMemsetAsync(h, 0, 2097152, stream);
        for (int t = 0; t < 16; ++t) {
            k_feat<<<512, 256, 0, stream>>>(WHT, xb, h, Sbuf, t);
            k_graph_ns<<<64, 256, 0, stream>>>(Lcat, Sbuf, h, out, t);
        }
    }
}

// Round 15
// 518.269 us; speedup vs baseline: 1.0605x; 1.0605x over previous
//
#include <hip/hip_runtime.h>
#include <stdint.h>

// ---------------------------------------------------------------------------
// RGNN layer: h_t = relu( sum_k L^{k+1} (x_t W_k + h_{t-1} H_k) ), h_{-1}=0
// B=8 T=16 N=1024 F=128 K=4.
//
//   Lcat [1024 n][4096 q],  q=(k,m):  Lcat[n][k*1024+m] = (L^{k+1})[n][m]
//   S    [8192 c=(b,m)][4096 q]     : S layout S[b][g][k][m]
//   Z[n][(b,g)] = sum_q Lcat[n][q] * S[..]; h = relu(Z); out = h (f32)
//
// Laws (r4,7,8,11,12,14): LDS staging mandatory; no in-kernel cross-block
// fences; split-K for L2 residency (<4MB/XCD); 16x16 frags conflict-free
// w/ XOR swizzle; GEMM time tracks LDS bytes -> 64x64 waves @ 2 blk/CU;
// setprio neutral; FUSED kernels must keep >=2 blk/CU (r14: 1 blk/CU fused
// lost 5us/step to barrier serialization).
//
// Round 15: fused combine(t-1)+feat(t) at grid 512 (16 c-cols/block, 4x1
// waves, 56KB LDS -> 2 blk/CU). Same sync structure as validated r14.
// Loop = {fused, graph} x16 + final combine. 37 dispatches.
// ---------------------------------------------------------------------------

typedef __bf16 bf16_t;
typedef __bf16 bf16x4 __attribute__((ext_vector_type(4)));
typedef __bf16 bf16x8 __attribute__((ext_vector_type(8)));
typedef float  f32x4  __attribute__((ext_vector_type(4)));

__device__ __forceinline__ void gload_lds16(const void* g, void* l) {
    __builtin_amdgcn_global_load_lds(
        (const __attribute__((address_space(1))) void*)g,
        (__attribute__((address_space(3))) void*)l,
        16, 0, 0);
}

template<int N> __device__ __forceinline__ void wait_vmcnt() {
    if constexpr (N == 0)       asm volatile("s_waitcnt vmcnt(0)" ::: "memory");
    else if constexpr (N == 2)  asm volatile("s_waitcnt vmcnt(2)" ::: "memory");
    else if constexpr (N == 3)  asm volatile("s_waitcnt vmcnt(3)" ::: "memory");
    else if constexpr (N == 4)  asm volatile("s_waitcnt vmcnt(4)" ::: "memory");
    else if constexpr (N == 6)  asm volatile("s_waitcnt vmcnt(6)" ::: "memory");
    else if constexpr (N == 8)  asm volatile("s_waitcnt vmcnt(8)" ::: "memory");
    else                        asm volatile("s_waitcnt vmcnt(16)" ::: "memory");
}

// ---- merged setup: L->Lcat/Lt, W/H->WHT, x->bf16 ---------------------------
// grid 8448: [0,4096) L, [4096,4352) WH (65536 elems), [4352,8448) x.

__global__ void k_setup(const float* __restrict__ x, const float* __restrict__ L,
                        const float* __restrict__ W, const float* __restrict__ H,
                        bf16_t* __restrict__ xb, bf16_t* __restrict__ Lcat,
                        bf16_t* __restrict__ Lt, bf16_t* __restrict__ WHT) {
    int bid = blockIdx.x;
    if (bid < 4096) {                       // L: 1024x1024
        int idx = bid * 256 + threadIdx.x;
        int n = idx >> 10, m = idx & 1023;
        float v = L[idx];
        Lcat[n * 4096 + m] = (bf16_t)v;
        Lt[m * 1024 + n]   = (bf16_t)v;
    } else if (bid < 4352) {                // WH: 4*128*128 = 65536
        int idx = (bid - 4096) * 256 + threadIdx.x;
        int k = idx >> 14, f = (idx >> 7) & 127, g = idx & 127;
        WHT[(k * 128 + g) * 256 + f]       = (bf16_t)W[idx];
        WHT[(k * 128 + g) * 256 + 128 + f] = (bf16_t)H[idx];
    } else {                                // x: 4194304 float4, grid-stride
        int i = (bid - 4352) * 256 + threadIdx.x;
        for (; i < 4194304; i += 4096 * 256) {
            float4 v = reinterpret_cast<const float4*>(x)[i];
            bf16x4 o = { (bf16_t)v.x, (bf16_t)v.y, (bf16_t)v.z, (bf16_t)v.w };
            reinterpret_cast<bf16x4*>(xb)[i] = o;
        }
    }
}

// ---- combine (final step + fallback): relu(sum Zp) -> h, out ---------------

__global__ __launch_bounds__(256)
void k_combine8(const bf16_t* __restrict__ Zp,  // [8][1024][1024] (n, c=(b,g))
                bf16_t* __restrict__ h, float* __restrict__ out, int t) {
    int i = blockIdx.x * 256 + threadIdx.x;
    int n  = i >> 7;
    int c8 = (i & 127) * 8;
    size_t o = (size_t)n * 1024 + c8;
    float s[8] = {};
    #pragma unroll
    for (int z = 0; z < 8; ++z) {
        bf16x8 v = *reinterpret_cast<const bf16x8*>(Zp + (size_t)z * 1048576 + o);
        #pragma unroll
        for (int j = 0; j < 8; ++j) s[j] += (float)v[j];
    }
    bf16x8 hb;
    float4 o0, o1;
    #pragma unroll
    for (int j = 0; j < 8; ++j) { s[j] = fmaxf(s[j], 0.f); hb[j] = (bf16_t)s[j]; }
    o0.x = s[0]; o0.y = s[1]; o0.z = s[2]; o0.w = s[3];
    o1.x = s[4]; o1.y = s[5]; o1.z = s[6]; o1.w = s[7];
    int b = c8 >> 7, g = c8 & 127;
    *reinterpret_cast<bf16x8*>(h + (size_t)b * 131072 + (size_t)n * 128 + g) = hb;
    float* op = out + (size_t)b * 2097152 + (size_t)t * 131072
                    + (size_t)n * 128 + g;
    *reinterpret_cast<float4*>(op)     = o0;
    *reinterpret_cast<float4*>(op + 4) = o1;
}

// ---- fused combine(t-1) + feature GEMM(t) ----------------------------------
// grid 512 (1D, XCD-swizzled), 2 blk/CU (56KB LDS). Block = 16 c-cols x all
// 128 g x all 4 taps; 4 waves 4x1 (wave = 32 g x 16 c, MF=2 NF=1).
// Phase 1: h rows for this block's 16 (b,m) from Zp (8 slices, fixed order,
// f32 sum, relu) -> swizzled LDS B-subtiles st=2,3; out(t-1) written.
// Phase 2: S_k[g][c] = WHT_k @ [x|h]^T, 16 (tap,kstep) iterations, 3-buf A.
template<bool FIRST>
__global__ __launch_bounds__(256)
void k_fused(const bf16_t* __restrict__ WHT, const bf16_t* __restrict__ xb,
             const bf16_t* __restrict__ Zp, bf16_t* __restrict__ Sbuf,
             float* __restrict__ out, int t)
{
    __shared__ __align__(16) bf16_t BsF[4 * 16 * 64];   // [st][16 c][64 k] 8KB
    __shared__ __align__(16) bf16_t AsF[3 * 128 * 64];  // [buf][128 g][64 k]

    const int tid  = threadIdx.x;
    const int lane = tid & 63;
    const int wave = tid >> 6;                 // wm = wave (4x1 grid)

    const int id = blockIdx.x;
    const int bx = (id & 7) * 64 + (id >> 3);  // bijective XCD swizzle, 512
    const int c0 = bx * 16;
    const int b  = c0 >> 10;                   // uniform per block
    const int mb = c0 & 1023;

    // ---- issue x-half B (st=0,1; 4KB = 1 chunk/thread) + first two A tiles
    {
        int off = tid * 16;                    // byte in BsF[0..4096)
        int st = off >> 11;
        int within = off & 2047;
        int row = within >> 7;                 // c-row 0..15
        int kel = ((within ^ ((row & 7) << 4)) & 127) >> 1;
        const bf16_t* src = xb + (size_t)b * 2097152 + (size_t)t * 131072
                          + (size_t)(mb + row) * 128 + st * 64 + kel;
        gload_lds16(src, (char*)BsF + off);
    }
    auto stageA = [&](int bufi, int s) {       // s = tap*4 + kstep
        const int k = s >> 2, st = s & 3;
        #pragma unroll
        for (int i = 0; i < 4; ++i) {
            int chunk = i * 256 + tid;
            int off = chunk * 16;
            int row = off >> 7;
            int kel = ((off ^ ((row & 7) << 4)) & 127) >> 1;
            const bf16_t* src = WHT + (size_t)(k * 128 + row) * 256
                              + st * 64 + kel;
            gload_lds16(src, (char*)AsF + bufi * 16384 + off);
        }
    };
    stageA(0, 0);
    stageA(1, 1);

    // ---- phase 1: combine(t-1) for this block's 16 rows ----
    {
        const int r  = tid >> 4;               // c-row 0..15
        const int g0 = (tid & 15) * 8;         // g base 0..120
        float s[8] = {};
        if (!FIRST) {
            size_t o = (size_t)(mb + r) * 1024 + b * 128 + g0;
            #pragma unroll
            for (int z = 0; z < 8; ++z) {
                bf16x8 v = *reinterpret_cast<const bf16x8*>(
                    Zp + (size_t)z * 1048576 + o);
                #pragma unroll
                for (int j = 0; j < 8; ++j) s[j] += (float)v[j];
            }
        }
        bf16x8 hv;
        #pragma unroll
        for (int j = 0; j < 8; ++j) {
            s[j] = fmaxf(s[j], 0.f);
            hv[j] = (bf16_t)s[j];
        }
        const int st  = 2 + (g0 >> 6);         // h subtile (features 128+g)
        const int kk2 = (g0 & 63) * 2;         // byte col within subtile
        int byte = st * 2048 + ((r * 128 + kk2) ^ ((r & 7) << 4));
        *reinterpret_cast<bf16x8*>((char*)BsF + byte) = hv;
        if (!FIRST) {
            float* op = out + (size_t)b * 2097152 + (size_t)(t - 1) * 131072
                      + (size_t)(mb + r) * 128 + g0;
            float4 o0, o1;
            o0.x = s[0]; o0.y = s[1]; o0.z = s[2]; o0.w = s[3];
            o1.x = s[4]; o1.y = s[5]; o1.z = s[6]; o1.w = s[7];
            *reinterpret_cast<float4*>(op)     = o0;
            *reinterpret_cast<float4*>(op + 4) = o1;
        }
    }
    __syncthreads();   // h in LDS visible; prologue DMA drained here too

    // ---- phase 2: 16 (tap,kstep) iterations, 3-buf counted A pipeline ----
    f32x4 acc[2] = {};
    bf16x4 outv[4][2];
    #pragma unroll
    for (int s = 0; s < 16; ++s) {
        if (s < 15) wait_vmcnt<4>(); else wait_vmcnt<0>();
        __builtin_amdgcn_s_barrier();
        __builtin_amdgcn_sched_barrier(0);
        if (s + 2 < 16) stageA((s + 2) % 3, s + 2);

        const int abase = (s % 3) * 16384;
        const int bbase = (s & 3) * 2048;      // st == kstep (x: 0,1; h: 2,3)
        #pragma unroll
        for (int kk = 0; kk < 2; ++kk) {
            bf16x8 af[2], bfr;
            const int klane = (kk * 32 + (lane >> 4) * 8) * 2;
            #pragma unroll
            for (int mf = 0; mf < 2; ++mf) {
                int row = wave * 32 + mf * 16 + (lane & 15);
                int bo = (row * 128 + klane) ^ ((row & 7) << 4);
                af[mf] = *reinterpret_cast<const bf16x8*>(
                             (char*)AsF + abase + bo);
            }
            {
                int row = lane & 15;
                int bo = (row * 128 + klane) ^ ((row & 7) << 4);
                bfr = *reinterpret_cast<const bf16x8*>(
                          (char*)BsF + bbase + bo);
            }
            #pragma unroll
            for (int mf = 0; mf < 2; ++mf)
                acc[mf] = __builtin_amdgcn_mfma_f32_16x16x32_bf16(
                    af[mf], bfr, acc[mf], 0, 0, 0);
        }
        __builtin_amdgcn_sched_barrier(0);
        if ((s & 3) == 3) {                    // tap finished -> park in regs
            const int k = s >> 2;
            #pragma unroll
            for (int mf = 0; mf < 2; ++mf) {
                #pragma unroll
                for (int r2 = 0; r2 < 4; ++r2)
                    outv[k][mf][r2] = (bf16_t)acc[mf][r2];
                acc[mf] = (f32x4){0.f, 0.f, 0.f, 0.f};
            }
        }
    }

    // ---- write S: col=(b,m), row=g; S[b][g][k][m] ----
    const int col = c0 + (lane & 15);
    #pragma unroll
    for (int k = 0; k < 4; ++k) {
        #pragma unroll
        for (int mf = 0; mf < 2; ++mf) {
            int gb = wave * 32 + mf * 16 + ((lane >> 4) * 4);
            #pragma unroll
            for (int r2 = 0; r2 < 4; ++r2) {
                Sbuf[(size_t)(col >> 10) * 524288 + (size_t)(gb + r2) * 4096
                     + (size_t)k * 1024 + (col & 1023)] = outv[k][mf][r2];
            }
        }
    }
}

// ---- GEMM body (16x16x32 MFMA, counted-vmcnt pipeline, NBUF=2 or 3) --------
template<int BM, int BN, int GX, int GY, int GZ, int KTOT,
         int EPI, int BADDR, int ZK, int DEC, int NBUF>
__device__ __forceinline__
void gemm_body(const bf16_t* __restrict__ A, int lda,
               const bf16_t* __restrict__ BT, int ldbt,
               const bf16_t* __restrict__ B2,
               bf16_t* __restrict__ Cb, float* __restrict__ Cf,
               int ldc, int t)
{
    constexpr int BK = 64;
    constexpr int WM = BM / 2, WN = BN / 2;
    constexpr int MF = WM / 16, NF = WN / 16;
    constexpr int NT = KTOT / BK;
    constexpr int NWG = GX * GY * GZ;
    constexpr int ACH = BM * 8;
    constexpr int BCH = BN * 8;
    constexpr int LPT = (ACH + BCH) / 256;

    __shared__ __align__(16) bf16_t As[NBUF][BM * BK];
    __shared__ __align__(16) bf16_t Bs[NBUF][BN * BK];

    const int tid  = threadIdx.x;
    const int lane = tid & 63;
    const int wave = tid >> 6;
    const int wm = wave >> 1, wn = wave & 1;

    const int id  = blockIdx.x;
    const int swz = (id & 7) * (NWG / 8) + (id >> 3);
    int bx, by, bz;
    if (DEC == 0) {
        bx = swz % GX; by = (swz / GX) % GY; bz = swz / (GX * GY);
    } else {
        by = swz % GY; bz = (swz / GY) % GZ; bx = swz / (GY * GZ);
    }

    const int m0 = by * BM;
    const int c0 = bx * BN;
    const int kb_ = bz;

    const bf16_t* Ap = (EPI == 1) ? (A + kb_ * 128 * 256) : A;

    f32x4 acc[MF][NF] = {};

    auto stage = [&](int bufi, int kt) {
        const int q0 = kt * BK + (ZK > 0 ? kb_ * ZK : 0);
        #pragma unroll
        for (int i = 0; i < ACH / 256; ++i) {
            int chunk = i * 256 + tid;
            int off = chunk * 16;
            int row = off >> 7;
            int kel = ((off ^ ((row & 7) << 4)) & 127) >> 1;
            const bf16_t* src = Ap + (size_t)(m0 + row) * lda + (q0 + kel);
            gload_lds16(src, (char*)(&As[bufi][0]) + off);
        }
        #pragma unroll
        for (int i = 0; i < BCH / 256; ++i) {
            int chunk = i * 256 + tid;
            int off = chunk * 16;
            int row = off >> 7;
            int kel = ((off ^ ((row & 7) << 4)) & 127) >> 1;
            int c = c0 + row;
            const bf16_t* src;
            if (BADDR == 0) {
                src = BT + (size_t)c * ldbt + (q0 + kel);
            } else {
                int f = q0 + kel;
                if (q0 < 128) {
                    src = BT + (size_t)(c >> 10) * 2097152
                             + (size_t)t * 131072
                             + (size_t)(c & 1023) * 128 + f;
                } else {
                    src = B2 + (size_t)c * 128 + (f - 128);
                }
            }
            gload_lds16(src, (char*)(&Bs[bufi][0]) + off);
        }
    };

    auto compute = [&](int cur) {
        #pragma unroll
        for (int kk = 0; kk < 2; ++kk) {
            bf16x8 af[MF], bfr[NF];
            const int klane = (kk * 32 + (lane >> 4) * 8) * 2;
            #pragma unroll
            for (int mf = 0; mf < MF; ++mf) {
                int row = wm * WM + mf * 16 + (lane & 15);
                int bo = (row * 128 + klane) ^ ((row & 7) << 4);
                af[mf] = *reinterpret_cast<const bf16x8*>(
                             (const char*)(&As[cur][0]) + bo);
            }
            #pragma unroll
            for (int nf = 0; nf < NF; ++nf) {
                int row = wn * WN + nf * 16 + (lane & 15);
                int bo = (row * 128 + klane) ^ ((row & 7) << 4);
                bfr[nf] = *reinterpret_cast<const bf16x8*>(
                              (const char*)(&Bs[cur][0]) + bo);
            }
            #pragma unroll
            for (int mf = 0; mf < MF; ++mf)
                #pragma unroll
                for (int nf = 0; nf < NF; ++nf)
                    acc[mf][nf] = __builtin_amdgcn_mfma_f32_16x16x32_bf16(
                        af[mf], bfr[nf], acc[mf][nf], 0, 0, 0);
        }
    };

    if constexpr (NBUF == 3) {
        stage(0, 0);
        stage(1, 1);
        for (int kt = 0; kt < NT; ++kt) {
            if (kt < NT - 1) wait_vmcnt<LPT>(); else wait_vmcnt<0>();
            __builtin_amdgcn_s_barrier();
            __builtin_amdgcn_sched_barrier(0);
            if (kt + 2 < NT) stage((kt + 2) % 3, kt + 2);
            compute(kt % 3);
            __builtin_amdgcn_sched_barrier(0);
        }
    } else {
        stage(0, 0);
        stage(1, 1);
        for (int kt = 0; kt < NT; ++kt) {
            if (kt > 0 && kt + 1 < NT) {
                __builtin_amdgcn_s_barrier();
                stage((kt + 1) & 1, kt + 1);
            }
            if (kt + 1 < NT) wait_vmcnt<LPT>();
            else             wait_vmcnt<0>();
            __builtin_amdgcn_s_barrier();
            __builtin_amdgcn_sched_barrier(0);
            compute(kt & 1);
            __builtin_amdgcn_sched_barrier(0);
        }
    }

    #pragma unroll
    for (int mf = 0; mf < MF; ++mf) {
        #pragma unroll
        for (int nf = 0; nf < NF; ++nf) {
            f32x4 v = acc[mf][nf];
            int col   = c0 + wn * WN + nf * 16 + (lane & 15);
            int rbase = m0 + wm * WM + mf * 16 + ((lane >> 4) * 4);
            #pragma unroll
            for (int r = 0; r < 4; ++r) {
                int row = rbase + r;
                float val = v[r];
                if (EPI == 0) {
                    Cb[(size_t)row * ldc + col] = (bf16_t)val;
                } else if (EPI == 1) {
                    Cb[(size_t)(col >> 10) * 524288 + (size_t)row * 4096
                       + (size_t)kb_ * 1024 + (col & 1023)] = (bf16_t)val;
                } else if (EPI == 2) {
                    val = fmaxf(val, 0.f);
                    int b = col >> 7, g = col & 127;
                    Cb[(size_t)b * 131072 + (size_t)row * 128 + g] = (bf16_t)val;
                    Cf[(size_t)b * 2097152 + (size_t)t * 131072
                       + (size_t)row * 128 + g] = val;
                } else {
                    Cb[(size_t)kb_ * 1048576 + (size_t)row * 1024 + col]
                        = (bf16_t)val;
                }
            }
        }
    }
}

// ---- flavor wrappers --------------------------------------------------------

__global__ __launch_bounds__(256)
void k_chain(const bf16_t* __restrict__ A, const bf16_t* __restrict__ BT,
             bf16_t* __restrict__ Cb) {
    gemm_body<64, 64, 16, 16, 1, 1024, 0, 0, 0, 0, 3>(
        A, 4096, BT, 1024, nullptr, Cb, nullptr, 4096, 0);
}

__global__ __launch_bounds__(256)
void k_feat(const bf16_t* __restrict__ WHT, const bf16_t* __restrict__ xb,
            const bf16_t* __restrict__ h, bf16_t* __restrict__ Sbuf, int t) {
    // fallback path only
    gemm_body<128, 64, 128, 1, 4, 256, 1, 1, 0, 1, 3>(
        WHT, 256, xb, 0, h, Sbuf, nullptr, 0, t);
}

__global__ __launch_bounds__(256)
void k_graph(const bf16_t* __restrict__ Lcat, const bf16_t* __restrict__ Sbuf,
             bf16_t* __restrict__ Zp) {
    gemm_body<128, 128, 8, 8, 8, 512, 3, 0, 512, 0, 2>(
        Lcat, 4096, Sbuf, 4096, nullptr, Zp, nullptr, 0, 0);
}

__global__ __launch_bounds__(256)
void k_graph_ns(const bf16_t* __restrict__ Lcat, const bf16_t* __restrict__ Sbuf,
                bf16_t* __restrict__ h, float* __restrict__ out, int t) {
    gemm_body<128, 128, 8, 8, 1, 4096, 2, 0, 0, 0, 3>(
        Lcat, 4096, Sbuf, 4096, nullptr, h, out, 0, t);
}

// ---- launch ---------------------------------------------------------------

extern "C" void kernel_launch(void* const* d_in, const int* in_sizes, int n_in,
                              void* d_out, int out_size, void* d_ws, size_t ws_size,
                              hipStream_t stream) {
    const float* x = (const float*)d_in[0];   // [8][16][1024][128]
    const float* L = (const float*)d_in[1];   // [1024][1024]
    const float* W = (const float*)d_in[2];   // [4][128][128]
    const float* H = (const float*)d_in[3];   // [4][128][128]
    float* out = (float*)d_out;               // [8][16][1024][128]

    char* ws = (char*)d_ws;
    bf16_t* xb   = (bf16_t*)(ws);              // 33,554,432 B
    bf16_t* Lcat = (bf16_t*)(ws + 33554432);   //  8,388,608 B [1024][4096]
    bf16_t* Lt   = (bf16_t*)(ws + 41943040);   //  2,097,152 B
    bf16_t* WHT  = (bf16_t*)(ws + 44040192);   //    262,144 B
    bf16_t* Sbuf = (bf16_t*)(ws + 44302336);   //  8,388,608 B (S layout)
    bf16_t* h    = (bf16_t*)(ws + 52690944);   //  2,097,152 B (fallback only)
    bf16_t* Zp   = (bf16_t*)(ws + 54788096);   // 16,777,216 B [8][1024][1024]
    if (ws_size < 54788096u) return;
    const bool bigws = (ws_size >= 71565312u);

    k_setup<<<8448, 256, 0, stream>>>(x, L, W, H, xb, Lcat, Lt, WHT);

    // L-power chain: block p = block(p-1) @ L (M=N=K=1024), 256 WGs
    for (int p = 1; p < 4; ++p) {
        k_chain<<<256, 256, 0, stream>>>(Lcat + (p - 1) * 1024, Lt,
                                         Lcat + p * 1024);
    }

    if (bigws) {
        for (int t = 0; t < 16; ++t) {
            // fused: combine(t-1) [h -> LDS, out(t-1)] + feat(t) -> Sbuf
            if (t == 0)
                k_fused<true><<<512, 256, 0, stream>>>(WHT, xb, Zp, Sbuf, out, t);
            else
                k_fused<false><<<512, 256, 0, stream>>>(WHT, xb, Zp, Sbuf, out, t);
            // graph: Zp[z] = Lcat[:,z*512:+512] @ S[z], split-K=8, 512 WGs
            k_graph<<<512, 256, 0, stream>>>(Lcat, Sbuf, Zp);
        }
        // final combine for t=15 (h write unused)
        k_combine8<<<512, 256, 0, stream>>>(Zp, h, out, 15);
    } else {
        hipMemsetAsync(h, 0, 2097152, stream);
        for (int t = 0; t < 16; ++t) {
            k_feat<<<512, 256, 0, stream>>>(WHT, xb, h, Sbuf, t);
            k_graph_ns<<<64, 256, 0, stream>>>(Lcat, Sbuf, h, out, t);
        }
    }
}

// Round 16
// 494.671 us; speedup vs baseline: 1.1111x; 1.0477x over previous
//
#include <hip/hip_runtime.h>
#include <stdint.h>

// ---------------------------------------------------------------------------
// RGNN layer: h_t = relu( sum_k L^{k+1} (x_t W_k + h_{t-1} H_k) ), h_{-1}=0
// B=8 T=16 N=1024 F=128 K=4.
//
//   Lcat [1024 n][4096 q],  q=(k,m):  Lcat[n][k*1024+m] = (L^{k+1})[n][m]
//   S    [8192 c=(b,m)][4096 q]     : S layout S[b][g][k][m]
//   Z[n][(b,g)] = sum_q Lcat[n][q] * S[..]; h = relu(Z); out = h (f32)
//
// Laws (r4,7,8,11,12,14,15): LDS staging mandatory; no in-kernel cross-block
// fences; split-K for L2 residency (<4MB/XCD); 16x16 frags conflict-free w/
// XOR swizzle; GEMM time tracks LDS bytes -> 64x64 waves @ 2 blk/CU optimal;
// setprio neutral; combine-into-feat fusion loses (r13-15: gaps are cheap,
// fused geometry costs more than the saved dispatch).
//
// Round 16 (consolidation): round-12 step structure (feat+graph+combine),
// merged k_setup (r14-validated), chain as 2 dispatches: L^2 (+transposed
// copy), then {L^3 = L^2 L, L^4 = L^2 L^2} concurrently at 2 blk/CU.
// ---------------------------------------------------------------------------

typedef __bf16 bf16_t;
typedef __bf16 bf16x4 __attribute__((ext_vector_type(4)));
typedef __bf16 bf16x8 __attribute__((ext_vector_type(8)));
typedef float  f32x4  __attribute__((ext_vector_type(4)));

__device__ __forceinline__ void gload_lds16(const void* g, void* l) {
    __builtin_amdgcn_global_load_lds(
        (const __attribute__((address_space(1))) void*)g,
        (__attribute__((address_space(3))) void*)l,
        16, 0, 0);
}

template<int N> __device__ __forceinline__ void wait_vmcnt() {
    if constexpr (N == 0)       asm volatile("s_waitcnt vmcnt(0)" ::: "memory");
    else if constexpr (N == 2)  asm volatile("s_waitcnt vmcnt(2)" ::: "memory");
    else if constexpr (N == 3)  asm volatile("s_waitcnt vmcnt(3)" ::: "memory");
    else if constexpr (N == 4)  asm volatile("s_waitcnt vmcnt(4)" ::: "memory");
    else if constexpr (N == 6)  asm volatile("s_waitcnt vmcnt(6)" ::: "memory");
    else if constexpr (N == 8)  asm volatile("s_waitcnt vmcnt(8)" ::: "memory");
    else                        asm volatile("s_waitcnt vmcnt(16)" ::: "memory");
}

// ---- merged setup: L->Lcat/Lt, W/H->WHT, x->bf16 (r14-validated) -----------
// grid 8448: [0,4096) L, [4096,4352) WH (65536 elems), [4352,8448) x.

__global__ void k_setup(const float* __restrict__ x, const float* __restrict__ L,
                        const float* __restrict__ W, const float* __restrict__ H,
                        bf16_t* __restrict__ xb, bf16_t* __restrict__ Lcat,
                        bf16_t* __restrict__ Lt, bf16_t* __restrict__ WHT) {
    int bid = blockIdx.x;
    if (bid < 4096) {                       // L: 1024x1024
        int idx = bid * 256 + threadIdx.x;
        int n = idx >> 10, m = idx & 1023;
        float v = L[idx];
        Lcat[n * 4096 + m] = (bf16_t)v;
        Lt[m * 1024 + n]   = (bf16_t)v;
    } else if (bid < 4352) {                // WH: 4*128*128 = 65536
        int idx = (bid - 4096) * 256 + threadIdx.x;
        int k = idx >> 14, f = (idx >> 7) & 127, g = idx & 127;
        WHT[(k * 128 + g) * 256 + f]       = (bf16_t)W[idx];
        WHT[(k * 128 + g) * 256 + 128 + f] = (bf16_t)H[idx];
    } else {                                // x: 4194304 float4, grid-stride
        int i = (bid - 4352) * 256 + threadIdx.x;
        for (; i < 4194304; i += 4096 * 256) {
            float4 v = reinterpret_cast<const float4*>(x)[i];
            bf16x4 o = { (bf16_t)v.x, (bf16_t)v.y, (bf16_t)v.z, (bf16_t)v.w };
            reinterpret_cast<bf16x4*>(xb)[i] = o;
        }
    }
}

// ---- combine: Z = relu(sum_{z<8} Zp_bf16[z]) -> h bf16, out f32 ------------

__global__ __launch_bounds__(256)
void k_combine8(const bf16_t* __restrict__ Zp,  // [8][1024][1024] (n, c=(b,g))
                bf16_t* __restrict__ h, float* __restrict__ out, int t) {
    int i = blockIdx.x * 256 + threadIdx.x;
    int n  = i >> 7;
    int c8 = (i & 127) * 8;
    size_t o = (size_t)n * 1024 + c8;
    float s[8] = {};
    #pragma unroll
    for (int z = 0; z < 8; ++z) {
        bf16x8 v = *reinterpret_cast<const bf16x8*>(Zp + (size_t)z * 1048576 + o);
        #pragma unroll
        for (int j = 0; j < 8; ++j) s[j] += (float)v[j];
    }
    bf16x8 hb;
    float4 o0, o1;
    #pragma unroll
    for (int j = 0; j < 8; ++j) { s[j] = fmaxf(s[j], 0.f); hb[j] = (bf16_t)s[j]; }
    o0.x = s[0]; o0.y = s[1]; o0.z = s[2]; o0.w = s[3];
    o1.x = s[4]; o1.y = s[5]; o1.z = s[6]; o1.w = s[7];
    int b = c8 >> 7, g = c8 & 127;
    *reinterpret_cast<bf16x8*>(h + (size_t)b * 131072 + (size_t)n * 128 + g) = hb;
    float* op = out + (size_t)b * 2097152 + (size_t)t * 131072
                    + (size_t)n * 128 + g;
    *reinterpret_cast<float4*>(op)     = o0;
    *reinterpret_cast<float4*>(op + 4) = o1;
}

// ---- GEMM body (16x16x32 MFMA, counted-vmcnt pipeline, NBUF=2 or 3) --------
// C[M][N] = A[M][KTOT] @ B[KTOT][N], B given as B^T rows (N rows, K contig).
// 4 waves 2x2, wave tile (BM/2)x(BN/2). Grid 1D, bijective XCD swizzle.
// EPI: 0 plain bf16   1 S-layout bf16   2 relu h+out   3 bf16 partial Zp[bz]
//      4 chain1: Lcat col 1024+ AND transposed copy into (bf16*)Cf
//      6 chain2: Lcat col 2048 + kb_*1024
// BADDR: 0 = BT rows; 1 = feature split x|h; 2 = chain2 (kb_ picks BT/B2).
// ZK: per-bz K offset.
template<int BM, int BN, int GX, int GY, int GZ, int KTOT,
         int EPI, int BADDR, int ZK, int DEC, int NBUF>
__device__ __forceinline__
void gemm_body(const bf16_t* __restrict__ A, int lda,
               const bf16_t* __restrict__ BT, int ldbt,
               const bf16_t* __restrict__ B2,
               bf16_t* __restrict__ Cb, float* __restrict__ Cf,
               int ldc, int t)
{
    constexpr int BK = 64;
    constexpr int WM = BM / 2, WN = BN / 2;
    constexpr int MF = WM / 16, NF = WN / 16;
    constexpr int NT = KTOT / BK;
    constexpr int NWG = GX * GY * GZ;
    constexpr int ACH = BM * 8;
    constexpr int BCH = BN * 8;
    constexpr int LPT = (ACH + BCH) / 256;

    __shared__ __align__(16) bf16_t As[NBUF][BM * BK];
    __shared__ __align__(16) bf16_t Bs[NBUF][BN * BK];

    const int tid  = threadIdx.x;
    const int lane = tid & 63;
    const int wave = tid >> 6;
    const int wm = wave >> 1, wn = wave & 1;

    const int id  = blockIdx.x;
    const int swz = (id & 7) * (NWG / 8) + (id >> 3);
    int bx, by, bz;
    if (DEC == 0) {
        bx = swz % GX; by = (swz / GX) % GY; bz = swz / (GX * GY);
    } else {
        by = swz % GY; bz = (swz / GY) % GZ; bx = swz / (GY * GZ);
    }

    const int m0 = by * BM;
    const int c0 = bx * BN;
    const int kb_ = bz;

    const bf16_t* Ap = (EPI == 1) ? (A + kb_ * 128 * 256) : A;

    f32x4 acc[MF][NF] = {};

    auto stage = [&](int bufi, int kt) {
        const int q0 = kt * BK + (ZK > 0 ? kb_ * ZK : 0);
        #pragma unroll
        for (int i = 0; i < ACH / 256; ++i) {
            int chunk = i * 256 + tid;
            int off = chunk * 16;
            int row = off >> 7;
            int kel = ((off ^ ((row & 7) << 4)) & 127) >> 1;
            const bf16_t* src = Ap + (size_t)(m0 + row) * lda + (q0 + kel);
            gload_lds16(src, (char*)(&As[bufi][0]) + off);
        }
        #pragma unroll
        for (int i = 0; i < BCH / 256; ++i) {
            int chunk = i * 256 + tid;
            int off = chunk * 16;
            int row = off >> 7;
            int kel = ((off ^ ((row & 7) << 4)) & 127) >> 1;
            int c = c0 + row;
            const bf16_t* src;
            if (BADDR == 0) {
                src = BT + (size_t)c * ldbt + (q0 + kel);
            } else if (BADDR == 2) {
                const bf16_t* bt = (kb_ == 0) ? BT : B2;
                src = bt + (size_t)c * ldbt + (q0 + kel);
            } else {
                int f = q0 + kel;
                if (q0 < 128) {
                    src = BT + (size_t)(c >> 10) * 2097152
                             + (size_t)t * 131072
                             + (size_t)(c & 1023) * 128 + f;
                } else {
                    src = B2 + (size_t)c * 128 + (f - 128);
                }
            }
            gload_lds16(src, (char*)(&Bs[bufi][0]) + off);
        }
    };

    auto compute = [&](int cur) {
        #pragma unroll
        for (int kk = 0; kk < 2; ++kk) {
            bf16x8 af[MF], bfr[NF];
            const int klane = (kk * 32 + (lane >> 4) * 8) * 2;
            #pragma unroll
            for (int mf = 0; mf < MF; ++mf) {
                int row = wm * WM + mf * 16 + (lane & 15);
                int bo = (row * 128 + klane) ^ ((row & 7) << 4);
                af[mf] = *reinterpret_cast<const bf16x8*>(
                             (const char*)(&As[cur][0]) + bo);
            }
            #pragma unroll
            for (int nf = 0; nf < NF; ++nf) {
                int row = wn * WN + nf * 16 + (lane & 15);
                int bo = (row * 128 + klane) ^ ((row & 7) << 4);
                bfr[nf] = *reinterpret_cast<const bf16x8*>(
                              (const char*)(&Bs[cur][0]) + bo);
            }
            #pragma unroll
            for (int mf = 0; mf < MF; ++mf)
                #pragma unroll
                for (int nf = 0; nf < NF; ++nf)
                    acc[mf][nf] = __builtin_amdgcn_mfma_f32_16x16x32_bf16(
                        af[mf], bfr[nf], acc[mf][nf], 0, 0, 0);
        }
    };

    if constexpr (NBUF == 3) {
        stage(0, 0);
        stage(1, 1);
        for (int kt = 0; kt < NT; ++kt) {
            if (kt < NT - 1) wait_vmcnt<LPT>(); else wait_vmcnt<0>();
            __builtin_amdgcn_s_barrier();
            __builtin_amdgcn_sched_barrier(0);
            if (kt + 2 < NT) stage((kt + 2) % 3, kt + 2);
            compute(kt % 3);
            __builtin_amdgcn_sched_barrier(0);
        }
    } else {
        stage(0, 0);
        stage(1, 1);
        for (int kt = 0; kt < NT; ++kt) {
            if (kt > 0 && kt + 1 < NT) {
                __builtin_amdgcn_s_barrier();
                stage((kt + 1) & 1, kt + 1);
            }
            if (kt + 1 < NT) wait_vmcnt<LPT>();
            else             wait_vmcnt<0>();
            __builtin_amdgcn_s_barrier();
            __builtin_amdgcn_sched_barrier(0);
            compute(kt & 1);
            __builtin_amdgcn_sched_barrier(0);
        }
    }

    // epilogue: 16x16 D map col=lane&15, row=(lane>>4)*4+r  [m89-verified]
    #pragma unroll
    for (int mf = 0; mf < MF; ++mf) {
        #pragma unroll
        for (int nf = 0; nf < NF; ++nf) {
            f32x4 v = acc[mf][nf];
            int col   = c0 + wn * WN + nf * 16 + (lane & 15);
            int rbase = m0 + wm * WM + mf * 16 + ((lane >> 4) * 4);
            if constexpr (EPI == 4) {
                // chain1: L^2 into Lcat cols [1024,2048) + transposed copy
                bf16x4 tv;
                #pragma unroll
                for (int r = 0; r < 4; ++r) {
                    float val = v[r];
                    Cb[(size_t)(rbase + r) * 4096 + 1024 + col] = (bf16_t)val;
                    tv[r] = (bf16_t)val;
                }
                *reinterpret_cast<bf16x4*>(
                    (bf16_t*)Cf + (size_t)col * 1024 + rbase) = tv;
            } else {
                #pragma unroll
                for (int r = 0; r < 4; ++r) {
                    int row = rbase + r;
                    float val = v[r];
                    if (EPI == 0) {
                        Cb[(size_t)row * ldc + col] = (bf16_t)val;
                    } else if (EPI == 1) {
                        Cb[(size_t)(col >> 10) * 524288 + (size_t)row * 4096
                           + (size_t)kb_ * 1024 + (col & 1023)] = (bf16_t)val;
                    } else if (EPI == 2) {
                        val = fmaxf(val, 0.f);
                        int b = col >> 7, g = col & 127;
                        Cb[(size_t)b * 131072 + (size_t)row * 128 + g]
                            = (bf16_t)val;
                        Cf[(size_t)b * 2097152 + (size_t)t * 131072
                           + (size_t)row * 128 + g] = val;
                    } else if (EPI == 3) {
                        Cb[(size_t)kb_ * 1048576 + (size_t)row * 1024 + col]
                            = (bf16_t)val;
                    } else {
                        // EPI == 6: chain2 -> Lcat cols 2048 + kb_*1024
                        Cb[(size_t)row * 4096 + 2048 + kb_ * 1024 + col]
                            = (bf16_t)val;
                    }
                }
            }
        }
    }
}

// ---- flavor wrappers --------------------------------------------------------

__global__ __launch_bounds__(256)
void k_chain(const bf16_t* __restrict__ A, const bf16_t* __restrict__ BT,
             bf16_t* __restrict__ Cb) {
    // fallback chain step: M=N=K=1024, 64x64 tiles, grid 256
    gemm_body<64, 64, 16, 16, 1, 1024, 0, 0, 0, 0, 3>(
        A, 4096, BT, 1024, nullptr, Cb, nullptr, 4096, 0);
}

__global__ __launch_bounds__(256)
void k_chain1(const bf16_t* __restrict__ Lcat, const bf16_t* __restrict__ Lt,
              bf16_t* __restrict__ Cb, bf16_t* __restrict__ Lt2) {
    // L^2 = L @ L -> Lcat cols [1024,2048) + Lt2 = (L^2)^T; grid 256
    gemm_body<64, 64, 16, 16, 1, 1024, 4, 0, 0, 0, 3>(
        Lcat, 4096, Lt, 1024, nullptr, Cb, (float*)Lt2, 0, 0);
}

__global__ __launch_bounds__(256)
void k_chain2(const bf16_t* __restrict__ A, const bf16_t* __restrict__ Lt,
              const bf16_t* __restrict__ Lt2, bf16_t* __restrict__ Cb) {
    // bz=0: L^3 = L^2 @ L;  bz=1: L^4 = L^2 @ L^2; grid 512 (2 blk/CU)
    gemm_body<64, 64, 16, 16, 2, 1024, 6, 2, 0, 0, 3>(
        A, 4096, Lt, 1024, Lt2, Cb, nullptr, 0, 0);
}

__global__ __launch_bounds__(256)
void k_feat(const bf16_t* __restrict__ WHT, const bf16_t* __restrict__ xb,
            const bf16_t* __restrict__ h, bf16_t* __restrict__ Sbuf, int t) {
    // M=128,N=8192,K=256 per tap; 128x64 tiles, grid 128*1*4 = 512
    gemm_body<128, 64, 128, 1, 4, 256, 1, 1, 0, 1, 3>(
        WHT, 256, xb, 0, h, Sbuf, nullptr, 0, t);
}

__global__ __launch_bounds__(256)
void k_graph(const bf16_t* __restrict__ Lcat, const bf16_t* __restrict__ Sbuf,
             bf16_t* __restrict__ Zp) {
    // M=1024,N=1024, split-K=8 (K=512/slice, one slice per XCD);
    // 128x128 tiles / 64x64 waves, grid 512, 2-buf, bf16 partials
    gemm_body<128, 128, 8, 8, 8, 512, 3, 0, 512, 0, 2>(
        Lcat, 4096, Sbuf, 4096, nullptr, Zp, nullptr, 0, 0);
}

__global__ __launch_bounds__(256)
void k_graph_ns(const bf16_t* __restrict__ Lcat, const bf16_t* __restrict__ Sbuf,
                bf16_t* __restrict__ h, float* __restrict__ out, int t) {
    // fallback: no split-K, K=4096; 128x128 tiles, grid 64, 3-buf
    gemm_body<128, 128, 8, 8, 1, 4096, 2, 0, 0, 0, 3>(
        Lcat, 4096, Sbuf, 4096, nullptr, h, out, 0, t);
}

// ---- launch ---------------------------------------------------------------

extern "C" void kernel_launch(void* const* d_in, const int* in_sizes, int n_in,
                              void* d_out, int out_size, void* d_ws, size_t ws_size,
                              hipStream_t stream) {
    const float* x = (const float*)d_in[0];   // [8][16][1024][128]
    const float* L = (const float*)d_in[1];   // [1024][1024]
    const float* W = (const float*)d_in[2];   // [4][128][128]
    const float* H = (const float*)d_in[3];   // [4][128][128]
    float* out = (float*)d_out;               // [8][16][1024][128]

    char* ws = (char*)d_ws;
    bf16_t* xb   = (bf16_t*)(ws);              // 33,554,432 B
    bf16_t* Lcat = (bf16_t*)(ws + 33554432);   //  8,388,608 B [1024][4096]
    bf16_t* Lt   = (bf16_t*)(ws + 41943040);   //  2,097,152 B
    bf16_t* WHT  = (bf16_t*)(ws + 44040192);   //    262,144 B
    bf16_t* Sbuf = (bf16_t*)(ws + 44302336);   //  8,388,608 B (S layout)
    bf16_t* h    = (bf16_t*)(ws + 52690944);   //  2,097,152 B
    bf16_t* Zp   = (bf16_t*)(ws + 54788096);   // 16,777,216 B [8][1024][1024]
    bf16_t* Lt2  = (bf16_t*)(ws + 71565312);   //  2,097,152 B (L^2)^T
    if (ws_size < 54788096u) return;
    const bool bigws = (ws_size >= 73662464u);

    hipMemsetAsync(h, 0, 2097152, stream);
    k_setup<<<8448, 256, 0, stream>>>(x, L, W, H, xb, Lcat, Lt, WHT);

    if (bigws) {
        // chain: L^2 (+transpose), then {L^3, L^4} concurrently
        k_chain1<<<256, 256, 0, stream>>>(Lcat, Lt, Lcat, Lt2);
        k_chain2<<<512, 256, 0, stream>>>(Lcat + 1024, Lt, Lt2, Lcat);
        for (int t = 0; t < 16; ++t) {
            // feature: S_k = WHT_k @ [x_t | h]^T, 512 WGs
            k_feat<<<512, 256, 0, stream>>>(WHT, xb, h, Sbuf, t);
            // graph: Zp[z] = Lcat[:,z*512:+512] @ S[z], split-K=8, 512 WGs
            k_graph<<<512, 256, 0, stream>>>(Lcat, Sbuf, Zp);
            // combine: relu(sum Zp) -> h, out
            k_combine8<<<512, 256, 0, stream>>>(Zp, h, out, t);
        }
    } else {
        for (int p = 1; p < 4; ++p) {
            k_chain<<<256, 256, 0, stream>>>(Lcat + (p - 1) * 1024, Lt,
                                             Lcat + p * 1024);
        }
        for (int t = 0; t < 16; ++t) {
            k_feat<<<512, 256, 0, stream>>>(WHT, xb, h, Sbuf, t);
            k_graph_ns<<<64, 256, 0, stream>>>(Lcat, Sbuf, h, out, t);
        }
    }
}